// Round 2
// baseline (609.677 us; speedup 1.0000x reference)
//
#include <hip/hip_runtime.h>
#include <hip/hip_bf16.h>

typedef _Float16 f16x8 __attribute__((ext_vector_type(8)));
typedef float    f32x4 __attribute__((ext_vector_type(4)));

#define T_SEQ 2048
#define C_DIM 1024
#define NH    16
#define DH    64

__device__ __forceinline__ unsigned short f2h(float f){
  _Float16 h = (_Float16)f;               // v_cvt_f16_f32, RTN
  return __builtin_bit_cast(unsigned short, h);
}

__global__ __launch_bounds__(256) void cvt_f32_f16(const float* __restrict__ src,
    unsigned short* __restrict__ dst, int n){
  int stride = gridDim.x * blockDim.x * 4;
  for (int i = (blockIdx.x * blockDim.x + threadIdx.x) * 4; i < n; i += stride){
    float4 v = *reinterpret_cast<const float4*>(src + i);
    ushort4 o;
    o.x = f2h(v.x); o.y = f2h(v.y); o.z = f2h(v.z); o.w = f2h(v.w);
    *reinterpret_cast<ushort4*>(dst + i) = o;
  }
}

__device__ __forceinline__ void gload_lds16(void* lds, const void* g){
  __builtin_amdgcn_global_load_lds(
      (const __attribute__((address_space(1))) void*)g,
      (__attribute__((address_space(3))) void*)lds, 16, 0, 0);
}

// C[m,n] = sum_k A[m,k]*B[n,k]; A:[M,K] f16, B:[N,K] f16. 128x128 tile, BK=64.
template<bool OUT_F16>
__global__ __launch_bounds__(256) void gemm_bt(const unsigned short* __restrict__ A,
    const unsigned short* __restrict__ B, void* __restrict__ Cout,
    int M, int N, int K)
{
  __shared__ alignas(16) unsigned short As[128*64];
  __shared__ alignas(16) unsigned short Bs[128*64];
  const int tid = threadIdx.x;
  const int l = tid & 63, w = tid >> 6;
  const int wr = w >> 1, wc = w & 1;
  const int bm = blockIdx.y, bn = blockIdx.x;

  const int srow = l >> 3;            // 0..7 within the 8-row chunk this wave-load covers
  const int g_kblk = (l & 7) ^ srow;  // pre-swizzled global k-block for this lane

  const f32x4 fzero = {0.f, 0.f, 0.f, 0.f};
  f32x4 acc[4][4];
#pragma unroll
  for (int m = 0; m < 4; ++m)
#pragma unroll
    for (int n = 0; n < 4; ++n) acc[m][n] = fzero;

  const int nkt = K >> 6;
  for (int kt = 0; kt < nkt; ++kt){
    __syncthreads();
#pragma unroll
    for (int i = 0; i < 4; ++i){
      int row = w*32 + i*8 + srow;
      gload_lds16(&As[(w*32 + i*8)*64],
                  A + (size_t)(bm*128 + row)*K + kt*64 + g_kblk*8);
      gload_lds16(&Bs[(w*32 + i*8)*64],
                  B + (size_t)(bn*128 + row)*K + kt*64 + g_kblk*8);
    }
    __syncthreads();
#pragma unroll
    for (int ks = 0; ks < 2; ++ks){
      f16x8 af[4], bfr[4];
#pragma unroll
      for (int m = 0; m < 4; ++m){
        int row = wr*64 + m*16 + (l & 15);
        af[m] = *reinterpret_cast<const f16x8*>(
            &As[row*64 + ((ks*4 + (l >> 4)) ^ (l & 7))*8]);
      }
#pragma unroll
      for (int n = 0; n < 4; ++n){
        int row = wc*64 + n*16 + (l & 15);
        bfr[n] = *reinterpret_cast<const f16x8*>(
            &Bs[row*64 + ((ks*4 + (l >> 4)) ^ (l & 7))*8]);
      }
#pragma unroll
      for (int m = 0; m < 4; ++m)
#pragma unroll
        for (int n = 0; n < 4; ++n)
          acc[m][n] = __builtin_amdgcn_mfma_f32_16x16x32_f16(af[m], bfr[n], acc[m][n], 0, 0, 0);
    }
  }

  const int r0 = (l >> 4) << 2;
  const int c0 = l & 15;
#pragma unroll
  for (int m = 0; m < 4; ++m){
    int row = bm*128 + wr*64 + m*16 + r0;
#pragma unroll
    for (int n = 0; n < 4; ++n){
      int col = bn*128 + wc*64 + n*16 + c0;
#pragma unroll
      for (int r = 0; r < 4; ++r){
        if (OUT_F16)
          reinterpret_cast<unsigned short*>(Cout)[(size_t)(row+r)*N + col] = f2h(acc[m][n][r]);
        else
          reinterpret_cast<float*>(Cout)[(size_t)(row+r)*N + col] = acc[m][n][r];
      }
    }
  }
}

// Flash attention: one block = one (b,h,64-row q block), 4 waves, KBLK=64.
__global__ __launch_bounds__(256) void attn_fwd(const unsigned short* __restrict__ qkv,
    const float* __restrict__ bias, unsigned short* __restrict__ yout)
{
  __shared__ alignas(16) unsigned short Qs[64*72];  // padded stride 72
  __shared__ alignas(16) unsigned short Ks[64*72];
  __shared__ alignas(16) unsigned short Vs[64*64];  // transposed [d][j], XOR-swizzled
  __shared__ alignas(16) unsigned short Ps[64*72];

  const int tid = threadIdx.x;
  const int l = tid & 63, w = tid >> 6;
  const int bid = blockIdx.x;
  const int qbi = 31 - (bid >> 5);       // heavy (long-row) q-blocks first
  const int b = (bid >> 4) & 1, h = bid & 15;
  const int q0 = qbi * 64;

  const size_t C3 = 3 * C_DIM;
  const unsigned short* qb_ = qkv + (size_t)b*T_SEQ*C3 + h*DH;
  const unsigned short* kb_ = qb_ + C_DIM;
  const unsigned short* vb_ = qb_ + 2*C_DIM;
  const float* bb_ = bias + (size_t)h*T_SEQ*T_SEQ;

  // Q tile: rows q0..q0+63, 64 cols
#pragma unroll
  for (int it = 0; it < 2; ++it){
    int idx = it*256 + tid;
    int row = idx >> 3, c = idx & 7;
    *reinterpret_cast<uint4*>(&Qs[row*72 + c*8]) =
        *reinterpret_cast<const uint4*>(qb_ + (size_t)(q0+row)*C3 + c*8);
  }

  const f32x4 fzero = {0.f, 0.f, 0.f, 0.f};
  f32x4 Of[4];
#pragma unroll
  for (int f = 0; f < 4; ++f) Of[f] = fzero;
  const float NEG_INF = -__builtin_inff();
  float mrow[4], lrow[4];
#pragma unroll
  for (int r = 0; r < 4; ++r){ mrow[r] = NEG_INF; lrow[r] = 0.f; }

  const int rbase = w*16 + ((l >> 4) << 2);
  const int cl = l & 15;
  const int nkt = qbi + 1;

  for (int kt = 0; kt < nkt; ++kt){
    const int k0 = kt * 64;
    __syncthreads();
    // stage K (row-major, padded)
#pragma unroll
    for (int it = 0; it < 2; ++it){
      int idx = it*256 + tid;
      int row = idx >> 3, c = idx & 7;
      *reinterpret_cast<uint4*>(&Ks[row*72 + c*8]) =
          *reinterpret_cast<const uint4*>(kb_ + (size_t)(k0+row)*C3 + c*8);
    }
    // stage V transposed + swizzled: Vs[d][jblk ^ (d&7)][j&7]
    {
      int d = tid & 63;
#pragma unroll
      for (int jj = 0; jj < 2; ++jj){
        int j0 = ((tid >> 6) + jj*4) * 8;
        unsigned short tmp[8] __attribute__((aligned(16)));
#pragma unroll
        for (int e = 0; e < 8; ++e)
          tmp[e] = vb_[(size_t)(k0 + j0 + e)*C3 + d];   // coalesced across lanes
        int blk = (j0 >> 3) ^ (d & 7);
        *reinterpret_cast<uint4*>(&Vs[d*64 + blk*8]) = *reinterpret_cast<const uint4*>(tmp);
      }
    }
    __syncthreads();

    // S = Q K^T  (wave w owns rows w*16..w*16+15, all 64 cols)
    f32x4 Sf[4];
#pragma unroll
    for (int f = 0; f < 4; ++f) Sf[f] = fzero;
    {
      const int arow = w*16 + (l & 15);
#pragma unroll
      for (int ks = 0; ks < 2; ++ks){
        f16x8 aq = *reinterpret_cast<const f16x8*>(&Qs[arow*72 + ks*32 + (l >> 4)*8]);
#pragma unroll
        for (int f = 0; f < 4; ++f){
          f16x8 bk = *reinterpret_cast<const f16x8*>(
              &Ks[(f*16 + (l & 15))*72 + ks*32 + (l >> 4)*8]);
          Sf[f] = __builtin_amdgcn_mfma_f32_16x16x32_f16(aq, bk, Sf[f], 0, 0, 0);
        }
      }
    }

    // logits = (S + bias) * 8, causal mask
    float logit[4][4];
#pragma unroll
    for (int f = 0; f < 4; ++f){
      int gcol = k0 + f*16 + cl;
#pragma unroll
      for (int r = 0; r < 4; ++r){
        int grow = q0 + rbase + r;
        float v = (Sf[f][r] + bb_[(size_t)grow*T_SEQ + gcol]) * 8.0f;
        logit[f][r] = (gcol <= grow) ? v : NEG_INF;
      }
    }

    // online softmax; row r lives in the 16 lanes sharing (l>>4)
#pragma unroll
    for (int r = 0; r < 4; ++r){
      float mx = fmaxf(fmaxf(logit[0][r], logit[1][r]), fmaxf(logit[2][r], logit[3][r]));
      mx = fmaxf(mx, __shfl_xor(mx, 1));
      mx = fmaxf(mx, __shfl_xor(mx, 2));
      mx = fmaxf(mx, __shfl_xor(mx, 4));
      mx = fmaxf(mx, __shfl_xor(mx, 8));
      float mnew = fmaxf(mrow[r], mx);
      float alpha = __expf(mrow[r] - mnew);   // expf(-inf)=0 on first tile
      float ps = 0.f;
#pragma unroll
      for (int f = 0; f < 4; ++f){
        float p = __expf(logit[f][r] - mnew); // -inf -> 0
        ps += p;
        Ps[(rbase + r)*72 + f*16 + cl] = f2h(p);
      }
      ps += __shfl_xor(ps, 1);
      ps += __shfl_xor(ps, 2);
      ps += __shfl_xor(ps, 4);
      ps += __shfl_xor(ps, 8);
      lrow[r] = lrow[r]*alpha + ps;
      mrow[r] = mnew;
#pragma unroll
      for (int f = 0; f < 4; ++f) Of[f][r] *= alpha;
    }

    // O += P V   (P rows of this wave only -> same-wave LDS dep, no barrier needed)
#pragma unroll
    for (int ks = 0; ks < 2; ++ks){
      f16x8 ap = *reinterpret_cast<const f16x8*>(
          &Ps[(w*16 + (l & 15))*72 + ks*32 + (l >> 4)*8]);
#pragma unroll
      for (int f = 0; f < 4; ++f){
        int d = f*16 + (l & 15);
        int blk = (ks*4 + (l >> 4)) ^ (d & 7);
        f16x8 bv = *reinterpret_cast<const f16x8*>(&Vs[d*64 + blk*8]);
        Of[f] = __builtin_amdgcn_mfma_f32_16x16x32_f16(ap, bv, Of[f], 0, 0, 0);
      }
    }
  }

  // epilogue: O / l  -> y[b, t, h*64+d] f16
#pragma unroll
  for (int f = 0; f < 4; ++f){
#pragma unroll
    for (int r = 0; r < 4; ++r){
      float o = Of[f][r] / lrow[r];
      int row = q0 + rbase + r;
      yout[((size_t)b*T_SEQ + row)*C_DIM + h*DH + f*16 + cl] = f2h(o);
    }
  }
}

extern "C" void kernel_launch(void* const* d_in, const int* in_sizes, int n_in,
                              void* d_out, int out_size, void* d_ws, size_t ws_size,
                              hipStream_t stream)
{
  const float* x  = (const float*)d_in[0];
  const float* pb = (const float*)d_in[1];
  const float* wa = (const float*)d_in[2];
  const float* wp = (const float*)d_in[3];

  unsigned short* xb  = (unsigned short*)d_ws;            // 4096x1024 f16
  unsigned short* wab = xb  + (size_t)4096*1024;          // 3072x1024
  unsigned short* wpb = wab + (size_t)3072*1024;          // 1024x1024
  unsigned short* qkv = wpb + (size_t)1024*1024;          // 4096x3072
  unsigned short* yb  = qkv + (size_t)4096*3072;          // 4096x1024

  cvt_f32_f16<<<1024, 256, 0, stream>>>(x,  xb,  4096*1024);
  cvt_f32_f16<<<1024, 256, 0, stream>>>(wa, wab, 3072*1024);
  cvt_f32_f16<<<256,  256, 0, stream>>>(wp, wpb, 1024*1024);

  gemm_bt<true ><<<dim3(24, 32), 256, 0, stream>>>(xb, wab, qkv, 4096, 3072, 1024);
  attn_fwd<<<1024, 256, 0, stream>>>(qkv, pb, yb);
  gemm_bt<false><<<dim3( 8, 32), 256, 0, stream>>>(yb, wpb, d_out, 4096, 1024, 1024);
}

// Round 4
// 479.182 us; speedup vs baseline: 1.2723x; 1.2723x over previous
//
#include <hip/hip_runtime.h>
#include <hip/hip_bf16.h>

typedef _Float16 f16x8 __attribute__((ext_vector_type(8)));
typedef float    f32x4 __attribute__((ext_vector_type(4)));

#define T_SEQ 2048
#define C_DIM 1024
#define NH    16
#define DH    64

__device__ __forceinline__ unsigned short f2h(float f){
  _Float16 h = (_Float16)f;               // v_cvt_f16_f32, RTN
  return __builtin_bit_cast(unsigned short, h);
}

__global__ __launch_bounds__(256) void cvt_f32_f16(const float* __restrict__ src,
    unsigned short* __restrict__ dst, int n){
  int stride = gridDim.x * blockDim.x * 4;
  for (int i = (blockIdx.x * blockDim.x + threadIdx.x) * 4; i < n; i += stride){
    float4 v = *reinterpret_cast<const float4*>(src + i);
    ushort4 o;
    o.x = f2h(v.x); o.y = f2h(v.y); o.z = f2h(v.z); o.w = f2h(v.w);
    *reinterpret_cast<ushort4*>(dst + i) = o;
  }
}

__device__ __forceinline__ void gload_lds16(void* lds, const void* g){
  __builtin_amdgcn_global_load_lds(
      (const __attribute__((address_space(1))) void*)g,
      (__attribute__((address_space(3))) void*)lds, 16, 0, 0);
}

// C[m,n] = sum_k A[m,k]*B[n,k]; A:[M,K] f16, B:[N,K] f16. 128x128 tile, BK=64.
template<bool OUT_F16>
__global__ __launch_bounds__(256) void gemm_bt(const unsigned short* __restrict__ A,
    const unsigned short* __restrict__ B, void* __restrict__ Cout,
    int M, int N, int K)
{
  __shared__ alignas(16) unsigned short As[128*64];
  __shared__ alignas(16) unsigned short Bs[128*64];
  const int tid = threadIdx.x;
  const int l = tid & 63, w = tid >> 6;
  const int wr = w >> 1, wc = w & 1;
  const int bm = blockIdx.y, bn = blockIdx.x;

  const int srow = l >> 3;
  const int g_kblk = (l & 7) ^ srow;

  const f32x4 fzero = {0.f, 0.f, 0.f, 0.f};
  f32x4 acc[4][4];
#pragma unroll
  for (int m = 0; m < 4; ++m)
#pragma unroll
    for (int n = 0; n < 4; ++n) acc[m][n] = fzero;

  const int nkt = K >> 6;
  for (int kt = 0; kt < nkt; ++kt){
    __syncthreads();
#pragma unroll
    for (int i = 0; i < 4; ++i){
      int row = w*32 + i*8 + srow;
      gload_lds16(&As[(w*32 + i*8)*64],
                  A + (size_t)(bm*128 + row)*K + kt*64 + g_kblk*8);
      gload_lds16(&Bs[(w*32 + i*8)*64],
                  B + (size_t)(bn*128 + row)*K + kt*64 + g_kblk*8);
    }
    __syncthreads();
#pragma unroll
    for (int ks = 0; ks < 2; ++ks){
      f16x8 af[4], bfr[4];
#pragma unroll
      for (int m = 0; m < 4; ++m){
        int row = wr*64 + m*16 + (l & 15);
        af[m] = *reinterpret_cast<const f16x8*>(
            &As[row*64 + ((ks*4 + (l >> 4)) ^ (l & 7))*8]);
      }
#pragma unroll
      for (int n = 0; n < 4; ++n){
        int row = wc*64 + n*16 + (l & 15);
        bfr[n] = *reinterpret_cast<const f16x8*>(
            &Bs[row*64 + ((ks*4 + (l >> 4)) ^ (l & 7))*8]);
      }
#pragma unroll
      for (int m = 0; m < 4; ++m)
#pragma unroll
        for (int n = 0; n < 4; ++n)
          acc[m][n] = __builtin_amdgcn_mfma_f32_16x16x32_f16(af[m], bfr[n], acc[m][n], 0, 0, 0);
    }
  }

  const int r0 = (l >> 4) << 2;
  const int c0 = l & 15;
#pragma unroll
  for (int m = 0; m < 4; ++m){
    int row = bm*128 + wr*64 + m*16 + r0;
#pragma unroll
    for (int n = 0; n < 4; ++n){
      int col = bn*128 + wc*64 + n*16 + c0;
#pragma unroll
      for (int r = 0; r < 4; ++r){
        if (OUT_F16)
          reinterpret_cast<unsigned short*>(Cout)[(size_t)(row+r)*N + col] = f2h(acc[m][n][r]);
        else
          reinterpret_cast<float*>(Cout)[(size_t)(row+r)*N + col] = acc[m][n][r];
      }
    }
  }
}

// Flash attention, software-pipelined: one block = one (b,h,64-row q block), 4 waves.
__global__ __launch_bounds__(256) void attn_fwd(const unsigned short* __restrict__ qkv,
    const float* __restrict__ bias, unsigned short* __restrict__ yout)
{
  __shared__ alignas(16) unsigned short Qs[64*64];      // XOR-swizzled, gload_lds
  __shared__ alignas(16) unsigned short Ks[2][64*64];   // XOR-swizzled, gload_lds, dbuf
  __shared__ alignas(16) unsigned short Vs[2][64*72];   // transposed [d][j], pad 72, dbuf
  __shared__ alignas(16) unsigned short Ps[64*72];      // pad 72

  const int tid = threadIdx.x;
  const int l = tid & 63, w = tid >> 6;
  const int bid = blockIdx.x;
  const int qbi = 31 - (bid >> 5);       // heavy (long-row) q-blocks first
  const int b = (bid >> 4) & 1, h = bid & 15;
  const int q0 = qbi * 64;

  const size_t C3 = 3 * C_DIM;
  const unsigned short* qb_ = qkv + (size_t)b*T_SEQ*C3 + h*DH;
  const unsigned short* kb_ = qb_ + C_DIM;
  const unsigned short* vb_ = qb_ + 2*C_DIM;
  const float* bb_ = bias + (size_t)h*T_SEQ*T_SEQ;

  const int srow = l >> 3;            // row within 8-row chunk
  const int scb  = (l & 7) ^ srow;    // pre-swizzled col-block for gload_lds

  // ---- prologue: stage Q, K[0] (async LDS), V[0] (regs -> transpose)
#pragma unroll
  for (int it = 0; it < 2; ++it){
    int r0 = w*16 + it*8;
    gload_lds16(&Qs[r0*64],    qb_ + (size_t)(q0 + r0 + srow)*C3 + scb*8);
    gload_lds16(&Ks[0][r0*64], kb_ + (size_t)(     r0 + srow)*C3 + scb*8);
  }
  {
    uint4 v0[2];
#pragma unroll
    for (int it = 0; it < 2; ++it){
      int idx = it*256 + tid;
      v0[it] = *reinterpret_cast<const uint4*>(vb_ + (size_t)(idx >> 3)*C3 + (idx & 7)*8);
    }
#pragma unroll
    for (int it = 0; it < 2; ++it){
      int idx = it*256 + tid;
      int row = idx >> 3, d0 = (idx & 7)*8;
      const unsigned short* t = reinterpret_cast<const unsigned short*>(&v0[it]);
#pragma unroll
      for (int e = 0; e < 8; ++e)
        Vs[0][(d0+e)*72 + row] = t[e];
    }
  }
  __syncthreads();

  const f32x4 fzero = {0.f, 0.f, 0.f, 0.f};
  f32x4 Of[4];
#pragma unroll
  for (int f = 0; f < 4; ++f) Of[f] = fzero;
  const float NEG_INF = -__builtin_inff();
  float mrow[4], lrow[4];
#pragma unroll
  for (int r = 0; r < 4; ++r){ mrow[r] = NEG_INF; lrow[r] = 0.f; }

  const int rbase = w*16 + ((l >> 4) << 2);
  const int cl = l & 15;
  const int nkt = qbi + 1;
  int cur = 0;

  for (int kt = 0; kt < nkt; ++kt){
    const int k0 = kt * 64;
    // 1) bias for THIS tile — issued first so its wait doesn't drain prefetches
    float breg[16];
#pragma unroll
    for (int f = 0; f < 4; ++f)
#pragma unroll
      for (int r = 0; r < 4; ++r)
        breg[f*4+r] = bb_[(size_t)(q0 + rbase + r)*T_SEQ + k0 + f*16 + cl];

    // 2) prefetch K(kt+1) -> Ks[cur^1] (async), V(kt+1) -> regs
    const int kn = (kt + 1 < nkt) ? k0 + 64 : k0;   // clamp (harmless reload on last iter)
#pragma unroll
    for (int it = 0; it < 2; ++it){
      int r0 = w*16 + it*8;
      gload_lds16(&Ks[cur^1][r0*64], kb_ + (size_t)(kn + r0 + srow)*C3 + scb*8);
    }
    uint4 vnew[2];
#pragma unroll
    for (int it = 0; it < 2; ++it){
      int idx = it*256 + tid;
      vnew[it] = *reinterpret_cast<const uint4*>(vb_ + (size_t)(kn + (idx >> 3))*C3 + (idx & 7)*8);
    }

    // 3) S = Q K^T from Ks[cur]
    f32x4 Sf[4];
#pragma unroll
    for (int f = 0; f < 4; ++f) Sf[f] = fzero;
    {
      const int arow = w*16 + (l & 15);
#pragma unroll
      for (int ks = 0; ks < 2; ++ks){
        int cb = ks*4 + (l >> 4);
        f16x8 aq = *reinterpret_cast<const f16x8*>(&Qs[arow*64 + (cb ^ (arow & 7))*8]);
#pragma unroll
        for (int f = 0; f < 4; ++f){
          int brow = f*16 + (l & 15);
          f16x8 bk = *reinterpret_cast<const f16x8*>(&Ks[cur][brow*64 + (cb ^ (brow & 7))*8]);
          Sf[f] = __builtin_amdgcn_mfma_f32_16x16x32_f16(aq, bk, Sf[f], 0, 0, 0);
        }
      }
    }

    // 4) logits = (S + bias) * 8, causal mask
    float logit[4][4];
#pragma unroll
    for (int f = 0; f < 4; ++f){
      int gcol = k0 + f*16 + cl;
#pragma unroll
      for (int r = 0; r < 4; ++r){
        int grow = q0 + rbase + r;
        float v = (Sf[f][r] + breg[f*4+r]) * 8.0f;
        logit[f][r] = (gcol <= grow) ? v : NEG_INF;
      }
    }

    // 5) online softmax; row r lives in the 16 lanes sharing (l>>4)
#pragma unroll
    for (int r = 0; r < 4; ++r){
      float mx = fmaxf(fmaxf(logit[0][r], logit[1][r]), fmaxf(logit[2][r], logit[3][r]));
      mx = fmaxf(mx, __shfl_xor(mx, 1));
      mx = fmaxf(mx, __shfl_xor(mx, 2));
      mx = fmaxf(mx, __shfl_xor(mx, 4));
      mx = fmaxf(mx, __shfl_xor(mx, 8));
      float mnew = fmaxf(mrow[r], mx);
      float alpha = __expf(mrow[r] - mnew);
      float ps = 0.f;
#pragma unroll
      for (int f = 0; f < 4; ++f){
        float p = __expf(logit[f][r] - mnew);
        ps += p;
        Ps[(rbase + r)*72 + f*16 + cl] = f2h(p);
      }
      ps += __shfl_xor(ps, 1);
      ps += __shfl_xor(ps, 2);
      ps += __shfl_xor(ps, 4);
      ps += __shfl_xor(ps, 8);
      lrow[r] = lrow[r]*alpha + ps;
      mrow[r] = mnew;
#pragma unroll
      for (int f = 0; f < 4; ++f) Of[f][r] *= alpha;
    }

    // 6) O += P V from Vs[cur]  (same-wave LDS dep on Ps)
#pragma unroll
    for (int ks = 0; ks < 2; ++ks){
      f16x8 ap = *reinterpret_cast<const f16x8*>(
          &Ps[(w*16 + (l & 15))*72 + ks*32 + (l >> 4)*8]);
#pragma unroll
      for (int f = 0; f < 4; ++f){
        int d = f*16 + (l & 15);
        f16x8 bv = *reinterpret_cast<const f16x8*>(
            &Vs[cur][d*72 + ks*32 + (l >> 4)*8]);
        Of[f] = __builtin_amdgcn_mfma_f32_16x16x32_f16(ap, bv, Of[f], 0, 0, 0);
      }
    }

    // 7) write V(kt+1) transpose into Vs[cur^1] (other buffer: no read hazard)
#pragma unroll
    for (int it = 0; it < 2; ++it){
      int idx = it*256 + tid;
      int row = idx >> 3, d0 = (idx & 7)*8;
      const unsigned short* t = reinterpret_cast<const unsigned short*>(&vnew[it]);
#pragma unroll
      for (int e = 0; e < 8; ++e)
        Vs[cur^1][(d0+e)*72 + row] = t[e];
    }
    __syncthreads();   // publishes Ks[cur^1] (gload_lds drained) + Vs[cur^1]
    cur ^= 1;
  }

  // epilogue: O / l  -> y[b, t, h*64+d] f16
#pragma unroll
  for (int f = 0; f < 4; ++f){
#pragma unroll
    for (int r = 0; r < 4; ++r){
      float o = Of[f][r] / lrow[r];
      int row = q0 + rbase + r;
      yout[((size_t)b*T_SEQ + row)*C_DIM + h*DH + f*16 + cl] = f2h(o);
    }
  }
}

extern "C" void kernel_launch(void* const* d_in, const int* in_sizes, int n_in,
                              void* d_out, int out_size, void* d_ws, size_t ws_size,
                              hipStream_t stream)
{
  const float* x  = (const float*)d_in[0];
  const float* pb = (const float*)d_in[1];
  const float* wa = (const float*)d_in[2];
  const float* wp = (const float*)d_in[3];

  unsigned short* xb  = (unsigned short*)d_ws;            // 4096x1024 f16
  unsigned short* wab = xb  + (size_t)4096*1024;          // 3072x1024
  unsigned short* wpb = wab + (size_t)3072*1024;          // 1024x1024
  unsigned short* qkv = wpb + (size_t)1024*1024;          // 4096x3072
  unsigned short* yb  = qkv + (size_t)4096*3072;          // 4096x1024

  cvt_f32_f16<<<1024, 256, 0, stream>>>(x,  xb,  4096*1024);
  cvt_f32_f16<<<1024, 256, 0, stream>>>(wa, wab, 3072*1024);
  cvt_f32_f16<<<256,  256, 0, stream>>>(wp, wpb, 1024*1024);

  gemm_bt<true ><<<dim3(24, 32), 256, 0, stream>>>(xb, wab, qkv, 4096, 3072, 1024);
  attn_fwd<<<1024, 256, 0, stream>>>(qkv, pb, yb);
  gemm_bt<false><<<dim3( 8, 32), 256, 0, stream>>>(yb, wpb, d_out, 4096, 1024, 1024);
}